// Round 11
// baseline (260.016 us; speedup 1.0000x reference)
//
#include <hip/hip_runtime.h>

#define B_ 32
#define C_ 128
#define H_ 32
#define W_ 32
#define WN 63
#define O_ 512              // 4*C
#define HTB (33 * 256)      // bytes per hT buffer
#define BIAS_ROW 32768      // shared bias row index in is_ws
#define PEXCH_OFF (2 * 33 * 256)        // pexch base within dynamic LDS
#define SCAN_LDS (PEXCH_OFF + 65536)    // 16896 + 64KB = 82432

typedef __attribute__((ext_vector_type(8))) short bf16x8;
typedef __attribute__((ext_vector_type(4))) float f32x4;
typedef __attribute__((ext_vector_type(4))) unsigned short us4;
typedef __attribute__((ext_vector_type(2))) unsigned int u32x2;

#define L2E 1.442695041f
#define L2E2 2.885390082f

#if __has_builtin(__builtin_amdgcn_exp2f)
__device__ __forceinline__ float EXP2(float x) { return __builtin_amdgcn_exp2f(x); }
#else
__device__ __forceinline__ float EXP2(float x) {
  float r; asm("v_exp_f32 %0, %1" : "=v"(r) : "v"(x)); return r;
}
#endif

__device__ __forceinline__ unsigned cvt_pk_bf16(float lo, float hi) {
  unsigned r;
  asm("v_cvt_pk_bf16_f32 %0, %1, %2" : "=v"(r) : "v"(lo), "v"(hi));
  return r;
}

__device__ __forceinline__ unsigned short f2bf(float f) {
  union { float f; unsigned u; } v; v.f = f;
  unsigned r = v.u + 0x7FFFu + ((v.u >> 16) & 1u);
  return (unsigned short)(r >> 16);
}
__device__ __forceinline__ float bf2f(unsigned short h) {
  union { unsigned u; float f; } v; v.u = ((unsigned)h) << 16;
  return v.f;
}

// LDS-only barrier (no vmcnt drain).
__device__ __forceinline__ void lds_barrier() {
  __builtin_amdgcn_sched_barrier(0);
  asm volatile("s_waitcnt lgkmcnt(0)" ::: "memory");
  __builtin_amdgcn_s_barrier();
  __builtin_amdgcn_sched_barrier(0);
}

// Diagonal-packed layout: step t's rows j in [jmin, jmax] contiguous at
// row = b*1024 + diag_off(t) + (j - jmin). Row = 512 u16 (1KB): i_s gates
// (prescaled incl. biases); after step t the scan overwrites bytes [0,512)
// of consumed rows with the f32 h outputs.
__device__ __forceinline__ int diag_off(int t) {
  return (t <= 31) ? (t * (t + 1) / 2) : (1024 - (63 - t) * (64 - t) / 2);
}

// ---------------------------------------------------------------------------
// Kernel 1: per (b, jq) block computes i_s for 4 j-rows (512x128 GEMM, K=128).
// ---------------------------------------------------------------------------
__global__ __launch_bounds__(512, 2)
void is_kernel(const float* __restrict__ x, const float* __restrict__ W_is,
               const float* __restrict__ b_is, const float* __restrict__ b_ss,
               unsigned short* __restrict__ is_ws) {
  const int bid = blockIdx.x;
  const int b = bid >> 3, jq = bid & 7;
  const int tid = threadIdx.x;
  const int w = tid >> 6, l = tid & 63;
  const int lg = l >> 4, lm = l & 15;

  // shared bias row (block 0 only): (b_is+b_ss)*SC
  if (bid == 0) {
    float v = (b_is[tid] + b_ss[tid]) * ((tid >> 7) == 3 ? L2E2 : L2E);
    is_ws[(size_t)BIAS_ROW * O_ + tid] = f2bf(v);
  }

  // xT: rows rr = jl*32 + c (128 rows) x 128 ch bf16, 16B-chunk swizzle by rr&15
  __shared__ __align__(16) unsigned short xT[128 * 128];
#pragma unroll
  for (int it = 0; it < 32; ++it) {
    int idx = it * 512 + tid;
    int c = idx & 31, jl = (idx >> 5) & 3, ch = idx >> 7;
    float v = x[((b * C_ + ch) * H_ + jq * 4 + jl) * W_ + c];
    int rr = jl * 32 + c;
    int byteCol = ch * 2;
    int addr = rr * 256 + (((byteCol >> 4) ^ (rr & 15)) << 4) + (byteCol & 15);
    *(unsigned short*)((char*)xT + addr) = f2bf(v);
  }
  __syncthreads();

  f32x4 acc[4][8];
#pragma unroll
  for (int g = 0; g < 4; ++g)
#pragma unroll
    for (int nt = 0; nt < 8; ++nt) acc[g][nt] = (f32x4){0.f, 0.f, 0.f, 0.f};

#pragma unroll
  for (int kf = 0; kf < 4; ++kf) {
    bf16x8 bfv[8];
#pragma unroll
    for (int nt = 0; nt < 8; ++nt) {
      int rr = (nt >> 1) * 32 + (nt & 1) * 16 + lm;
      int chunk = kf * 4 + lg;
      int addr = rr * 256 + ((chunk ^ (rr & 15)) << 4);
      bfv[nt] = *(const bf16x8*)((const char*)xT + addr);
    }
#pragma unroll
    for (int g = 0; g < 4; ++g) {
      const int o = g * 128 + 16 * w + lm;
      const float* wp = W_is + o * C_ + kf * 32 + lg * 8;
      f32x4 wa = *(const f32x4*)(wp);
      f32x4 wb = *(const f32x4*)(wp + 4);
      bf16x8 af;
      af[0] = (short)f2bf(wa[0]); af[1] = (short)f2bf(wa[1]);
      af[2] = (short)f2bf(wa[2]); af[3] = (short)f2bf(wa[3]);
      af[4] = (short)f2bf(wb[0]); af[5] = (short)f2bf(wb[1]);
      af[6] = (short)f2bf(wb[2]); af[7] = (short)f2bf(wb[3]);
#pragma unroll
      for (int nt = 0; nt < 8; ++nt)
        acc[g][nt] = __builtin_amdgcn_mfma_f32_16x16x32_bf16(af, bfv[nt], acc[g][nt], 0, 0, 0);
    }
  }

#pragma unroll
  for (int g = 0; g < 4; ++g) {
    const float sc = (g == 3) ? L2E2 : L2E;
    const int ob = g * 128 + 16 * w + lg * 4;
#pragma unroll
    for (int nt = 0; nt < 8; ++nt) {
      int jl = nt >> 1;
      int c = (nt & 1) * 16 + lm;
      int j = jq * 4 + jl;
      int t = j + c;
      int jmin = (t > 31) ? (t - 31) : 0;
      us4 st;
#pragma unroll
      for (int r = 0; r < 4; ++r)
        st[r] = f2bf((acc[g][nt][r] + b_is[ob + r] + b_ss[ob + r]) * sc);
      *(us4*)(is_ws + (size_t)(b * 1024 + diag_off(t) + (j - jmin)) * O_ + ob) = st;
    }
  }
}

// ---------------------------------------------------------------------------
// Kernel 2: diagonal scan, 16-wave K-split. 32 blocks x 1024 threads.
// Wave (w, kh): channels [16w,16w+16); kh=0 holds W0 (applied to h_up rows),
// kh=1 holds W1 (applied to h rows). Each computes partials for BOTH j-halves
// (32 MFMA), publishes the other-half partial via LDS pexch (conflict-free,
// [slot][g][lane] 16B), and owns the cell for j-half n==kh. Two LDS-only
// barriers per step. 64 weight VGPR/wave -> fits 128-VGPR cap at 4 waves/SIMD.
// ---------------------------------------------------------------------------
__global__ __launch_bounds__(1024, 4)
void scan_kernel(const float* __restrict__ Wss,
                 unsigned short* __restrict__ is_ws) {
  extern __shared__ __align__(16) char lds[];
  unsigned short* hT = (unsigned short*)lds;  // [2][33][128] bf16, swizzled
  char* pexch = lds + PEXCH_OFF;              // 64 slots x 1024B

  const int b = blockIdx.x;
  const int tid = threadIdx.x;
  const int v = tid >> 6;
  const int kh = v & 1;          // weight half + owned j-half
  const int w = v >> 1;          // channel group 0..7
  const int l = tid & 63;
  const int lg = l >> 4, lm = l & 15;
  const int chW = 16 * w;
  const int jOwn = kh * 16 + lm;
  const int jOth = (kh ^ 1) * 16 + lm;
  float* ows = (float*)is_ws;

  for (int i = tid; i < 2 * 33 * 128; i += 1024) hT[i] = 0;

  // Own-half weights, prescaled: A[g][kf], ch = kf*32 + lg*8 + e.
  // Wss interleaved (W0,W1) pairs -> element p = float index 2p+kh.
  bf16x8 A[4][4];
#pragma unroll
  for (int g = 0; g < 4; ++g) {
    const float sc = (g == 3) ? L2E2 : L2E;
    const int o = g * 128 + chW + lm;
#pragma unroll
    for (int kf = 0; kf < 4; ++kf) {
      const int ch = kf * 32 + lg * 8;
      const float* wp = Wss + (o * C_ + ch) * 2 + kh;
      bf16x8 a;
      a[0] = (short)f2bf(wp[0]  * sc);
      a[1] = (short)f2bf(wp[2]  * sc);
      a[2] = (short)f2bf(wp[4]  * sc);
      a[3] = (short)f2bf(wp[6]  * sc);
      a[4] = (short)f2bf(wp[8]  * sc);
      a[5] = (short)f2bf(wp[10] * sc);
      a[6] = (short)f2bf(wp[12] * sc);
      a[7] = (short)f2bf(wp[14] * sc);
      A[g][kf] = a;
    }
  }

  // hT read rows: kh=0 reads h_up rows (j-1, row 32 = zero row for j==0);
  // kh=1 reads h rows (j). Same for both target halves.
  const int rrOwn = kh ? jOwn : ((jOwn == 0) ? 32 : jOwn - 1);
  const int rrOth = kh ? jOth : (jOth - 1);  // kh=0: jOth=16+lm, never 0

  // pexch: slot(w,n) holds n-half partials; writer = wave (w, n^1).
  const int exWr = (w * 8 + kh * 4) * 1024 + l * 16;        // slot n = kh^1 -> (w*2+(kh^1))*4 ... writer index
  const int exRd = (w * 8 + (kh ^ 1) * 4) * 1024 + l * 16;  // slot n = kh
  // NOTE: slot(w,n) base = (w*2+n)*4*1024. Writer (other-n = kh^1 target):
  //   (w*2 + (kh^1))*4*1024 = w*8*1024 + (kh^1)*4*1024. Reader (own n = kh):
  //   (w*2 + kh)*4*1024.  (exWr/exRd above are written accordingly, swapped.)

  const int exWrB = (w * 8 + ((kh ^ 1) * 4)) * 1024 + l * 16;
  const int exRdB = (w * 8 + (kh * 4)) * 1024 + l * 16;

  int wAddrLane;
  {
    int byteCol = chW * 2 + lg * 8;
    wAddrLane = jOwn * 256 + (((byteCol >> 4) ^ (jOwn & 15)) << 4) + (byteCol & 15);
  }

  float cst[4] = {0.f, 0.f, 0.f, 0.f};

  __syncthreads();

  auto step_body = [&](int t, int rOff, int wOff) {
    const bool ownActive = (t < 47) || (kh == 1);  // own n = kh
    const bool othActive = (t < 47) || (kh == 0);  // other n = kh^1
    const int jminT = (t > 31) ? (t - 31) : 0;
    const int rowBase = b * 1024 + diag_off(t) - jminT;

    f32x4 accOwn[4], accOth[4];
#pragma unroll
    for (int g = 0; g < 4; ++g) {
      accOwn[g] = (f32x4){0.f, 0.f, 0.f, 0.f};
      accOth[g] = (f32x4){0.f, 0.f, 0.f, 0.f};
    }

    // ---- partial GEMM: other half first, then own ----
    if (othActive) {
#pragma unroll
      for (int kf = 0; kf < 4; ++kf) {
        const int chunk = kf * 4 + lg;
        const int addr = rOff + rrOth * 256 + ((chunk ^ (rrOth & 15)) << 4);
        bf16x8 bfv = *(const bf16x8*)((const char*)hT + addr);
#pragma unroll
        for (int g = 0; g < 4; ++g)
          accOth[g] = __builtin_amdgcn_mfma_f32_16x16x32_bf16(A[g][kf], bfv, accOth[g], 0, 0, 0);
      }
    }
    if (ownActive) {
#pragma unroll
      for (int kf = 0; kf < 4; ++kf) {
        const int chunk = kf * 4 + lg;
        const int addr = rOff + rrOwn * 256 + ((chunk ^ (rrOwn & 15)) << 4);
        bf16x8 bfv = *(const bf16x8*)((const char*)hT + addr);
#pragma unroll
        for (int g = 0; g < 4; ++g)
          accOwn[g] = __builtin_amdgcn_mfma_f32_16x16x32_bf16(A[g][kf], bfv, accOwn[g], 0, 0, 0);
      }
    }

    // ---- own-half i_s load (consumed after the exchange barrier) ----
    us4 isv[4];
    if (ownActive) {
      const bool valid = ((unsigned)(t - jOwn) < 32u);
      const int row = valid ? (rowBase + jOwn) : BIAS_ROW;
      const unsigned short* p = is_ws + (size_t)row * O_ + chW + lg * 4;
#pragma unroll
      for (int g = 0; g < 4; ++g) isv[g] = *(const us4*)(p + g * 128);
    }

    // ---- publish other-half partials ----
    if (othActive) {
#pragma unroll
      for (int g = 0; g < 4; ++g)
        *(f32x4*)(pexch + exWrB + g * 1024) = accOth[g];
    }

    lds_barrier();  // exchange visible

    if (ownActive) {
      const int c = t - jOwn;
      const bool inband = ((unsigned)c < 32u);
      f32x4 ov;
#pragma unroll
      for (int g = 0; g < 4; ++g) {
        f32x4 pg = *(const f32x4*)(pexch + exRdB + g * 1024);
#pragma unroll
        for (int r = 0; r < 4; ++r)
          accOwn[g][r] += pg[r] + bf2f(isv[g][r]);
      }
#pragma unroll
      for (int r = 0; r < 4; ++r) {
        float eo = EXP2(-accOwn[0][r]);
        float ef = EXP2(-accOwn[1][r]);
        float ei = EXP2(-accOwn[2][r]);
        float eg = EXP2(-accOwn[3][r]);
        float Af = 1.f + ef, Bi = 1.f + ei, Gg = 1.f + eg;
        float BG = Bi * Gg;
        float num = cst[r] * BG + (1.f - eg) * Af;
        float cn = num * __builtin_amdgcn_rcpf(Af * BG);
        cst[r] = cn;
        float ec = EXP2(cn * -L2E2);
        float hn = (1.f - ec) * __builtin_amdgcn_rcpf((1.f + ec) * (1.f + eo));
        ov[r] = hn;
      }
      if (inband)
        *(f32x4*)(ows + (size_t)(rowBase + jOwn) * 256 + chW + lg * 4) = ov;
      u32x2 hb;
      hb[0] = cvt_pk_bf16(ov[0], ov[1]);
      hb[1] = cvt_pk_bf16(ov[2], ov[3]);
      *(u32x2*)((char*)hT + wOff + wAddrLane) = hb;
    }

    lds_barrier();  // h(t) complete
  };

  for (int t = 0; t < WN - 1; t += 2) {
    step_body(t, 0, HTB);
    step_body(t + 1, HTB, 0);
  }
  step_body(WN - 1, 0, HTB);
}

// ---------------------------------------------------------------------------
// Kernel 3: unpack diag-packed f32 h rows -> out[b][ch][j][c].
// ---------------------------------------------------------------------------
__global__ __launch_bounds__(256, 4)
void unpack_kernel(const float* __restrict__ ows, float* __restrict__ out) {
  const int bid = blockIdx.x;  // b*32 + j
  const int b = bid >> 5, j = bid & 31;
  const int tid = threadIdx.x;

  __shared__ float tile[32 * 129];  // [c][ch], pad 129 vs bank conflicts

  {
    const int ch = tid & 127;
    const int half = tid >> 7;  // 2 rows per pass
#pragma unroll
    for (int q = 0; q < 16; ++q) {
      int c = q * 2 + half;
      int t = j + c;
      int jmin = (t > 31) ? (t - 31) : 0;
      size_t row = (size_t)(b * 1024 + diag_off(t) + (j - jmin));
      tile[c * 129 + ch] = ows[row * 256 + ch];
    }
  }
  __syncthreads();

  {
    const int c = tid & 31;
    const int ch0 = tid >> 5;  // 0..7
#pragma unroll
    for (int q = 0; q < 16; ++q) {
      int ch = q * 8 + ch0;
      out[((size_t)(b * C_ + ch) * H_ + j) * W_ + c] = tile[c * 129 + ch];
    }
  }
}

// ---------------------------------------------------------------------------
extern "C" void kernel_launch(void* const* d_in, const int* in_sizes, int n_in,
                              void* d_out, int out_size, void* d_ws, size_t ws_size,
                              hipStream_t stream) {
  const float* x    = (const float*)d_in[0];
  const float* W_is = (const float*)d_in[1];
  const float* b_is = (const float*)d_in[2];
  const float* W_ss = (const float*)d_in[3];
  const float* b_ss = (const float*)d_in[4];
  float* out = (float*)d_out;
  unsigned short* is_ws = (unsigned short*)d_ws;  // 32 MiB diag rows + bias row

  (void)hipFuncSetAttribute((const void*)scan_kernel,
                            hipFuncAttributeMaxDynamicSharedMemorySize, SCAN_LDS);
  is_kernel<<<dim3(B_ * 8), dim3(512), 0, stream>>>(x, W_is, b_is, b_ss, is_ws);
  scan_kernel<<<dim3(B_), dim3(1024), SCAN_LDS, stream>>>(W_ss, is_ws);
  unpack_kernel<<<dim3(B_ * H_), dim3(256), 0, stream>>>((const float*)is_ws, out);
}